// Round 3
// baseline (130.481 us; speedup 1.0000x reference)
//
#include <hip/hip_runtime.h>

// GraphClusterReshape: out[m, k*64 + f] = nidx[m,k] < 0 ? 0 : features[nidx[m,k], f]
// features: [100000, 64] f32 (25.6 MB), nidx: [50000, 32] i32, out: [50000, 2048] f32 (409.6 MB).
//
// R1 analysis: 123.5 us ~= (410 MB write + ~330 MB gather fetch) / 6.3 TB/s.
// The streaming output writes evict the 25.6 MB features array from L2/L3,
// turning the gather into HBM traffic. Fix: NON-TEMPORAL stores for out
// (write-once data, nt flag avoids cache pollution) so features stay
// cache-resident and gather reads hit L2/L3.
//
// R2 fix: __builtin_nontemporal_store needs a clang vector type, not HIP's
// struct float4 -> use ext_vector_type(4).
//
// Layout: one thread per output float4 (16 B/lane). 16 lanes = one neighbor
// row (64 floats); stores 1 KB contiguous per wave; feature reads 256 B
// contiguous per 16-lane group.

typedef float f32x4 __attribute__((ext_vector_type(4)));

constexpr int K_NEIGH = 32;
constexpr int F4 = 16;        // 64 floats = 16 float4 per feature row
// output row = K_NEIGH * F4 = 512 float4  -> t>>9 = m, t&511 = q

__global__ void gcr_gather_kernel(const f32x4* __restrict__ feat4,
                                  const int* __restrict__ nidx,
                                  f32x4* __restrict__ out4,
                                  long long total4) {
    long long t = (long long)blockIdx.x * blockDim.x + threadIdx.x;
    const long long stride = (long long)gridDim.x * blockDim.x;
    for (; t < total4; t += stride) {
        const int m = (int)(t >> 9);       // / 512 float4 per output row
        const int q = (int)(t & 511);
        const int k = q >> 4;              // neighbor slot
        const int e = q & 15;              // float4 index within feature row
        const int idx = __builtin_nontemporal_load(&nidx[m * K_NEIGH + k]);
        f32x4 v;
        if (idx < 0) {
            v = (f32x4)(0.f);
        } else {
            v = feat4[(long long)idx * F4 + e];   // keep cached: 25.6 MB working set
        }
        __builtin_nontemporal_store(v, &out4[t]); // write-once: bypass L2/L3
    }
}

extern "C" void kernel_launch(void* const* d_in, const int* in_sizes, int n_in,
                              void* d_out, int out_size, void* d_ws, size_t ws_size,
                              hipStream_t stream) {
    const f32x4* feat4 = (const f32x4*)d_in[0];   // features [100000, 64] f32
    const int*   nidx  = (const int*)d_in[1];     // nidx [50000, 32] i32
    f32x4*       out4  = (f32x4*)d_out;           // [50000, 2048] f32

    const long long total4 = (long long)out_size / 4;   // 25.6M float4

    const int block = 256;
    long long want = (total4 + block - 1) / block;
    int grid = (int)(want < 2048 ? want : 2048);    // grid-stride, 8 blocks/CU -> full occupancy

    gcr_gather_kernel<<<grid, block, 0, stream>>>(feat4, nidx, out4, total4);
}